// Round 1
// baseline (258.132 us; speedup 1.0000x reference)
//
#include <hip/hip_runtime.h>
#include <hip/hip_bf16.h>
#include <cstdint>
#include <cstddef>

// Problem constants (fixed by setup_inputs)
#define B_   8
#define N_   256
#define DEG_ 32
#define H_   768
#define NH_  12
#define DH_  64
#define R_   64
#define E_   (B_*N_*DEG_)   // 65536
#define M_   (B_*N_)        // 2048

// ---------------- fused QKV GEMM (fp32, LDS-tiled) ----------------
// C[m,n] = X[m,:] @ W[:,n] + b[n] for W in {Wq,Wk,Wv}, sharing the X tile.
#define TM 64
#define TN 64
#define TK 16

__global__ __launch_bounds__(256, 2)
void qkv_gemm(const float* __restrict__ X,
              const float* __restrict__ Wq, const float* __restrict__ bq,
              const float* __restrict__ Wk, const float* __restrict__ bk,
              const float* __restrict__ Wv, const float* __restrict__ bv,
              float* __restrict__ Qo, float* __restrict__ Ko, float* __restrict__ Vo)
{
    __shared__ float Xs[TM][TK + 1];     // +1 pad breaks bank conflicts on column reads
    __shared__ float Ws[3][TK][TN];

    const int t  = threadIdx.x;
    const int tx = t & 15;               // n-quad
    const int ty = t >> 4;               // m-quad
    const int m0 = blockIdx.y * TM;
    const int n0 = blockIdx.x * TN;

    float acc[3][4][4];
    #pragma unroll
    for (int mt = 0; mt < 3; ++mt)
        #pragma unroll
        for (int i = 0; i < 4; ++i)
            #pragma unroll
            for (int j = 0; j < 4; ++j)
                acc[mt][i][j] = 0.f;

    const float* Wp[3] = {Wq, Wk, Wv};

    // staging indices
    const int xrow = t >> 2;             // 0..63
    const int xcol = (t & 3) * 4;        // 0,4,8,12
    const int wrow = t >> 4;             // 0..15
    const int wcol = (t & 15) * 4;       // 0..60

    for (int kt = 0; kt < H_; kt += TK) {
        // stage X tile (64x16) — one float4 per thread
        {
            const float4 xv = *(const float4*)(X + (size_t)(m0 + xrow) * H_ + kt + xcol);
            Xs[xrow][xcol + 0] = xv.x;
            Xs[xrow][xcol + 1] = xv.y;
            Xs[xrow][xcol + 2] = xv.z;
            Xs[xrow][xcol + 3] = xv.w;
        }
        // stage 3 W tiles (16x64 each) — one float4 per thread per matrix
        #pragma unroll
        for (int mt = 0; mt < 3; ++mt) {
            const float4 wv = *(const float4*)(Wp[mt] + (size_t)(kt + wrow) * H_ + n0 + wcol);
            *(float4*)&Ws[mt][wrow][wcol] = wv;
        }
        __syncthreads();

        #pragma unroll
        for (int k = 0; k < TK; ++k) {
            float a0 = Xs[ty * 4 + 0][k];
            float a1 = Xs[ty * 4 + 1][k];
            float a2 = Xs[ty * 4 + 2][k];
            float a3 = Xs[ty * 4 + 3][k];
            #pragma unroll
            for (int mt = 0; mt < 3; ++mt) {
                const float4 bv4 = *(const float4*)&Ws[mt][k][tx * 4];
                acc[mt][0][0] += a0 * bv4.x; acc[mt][0][1] += a0 * bv4.y;
                acc[mt][0][2] += a0 * bv4.z; acc[mt][0][3] += a0 * bv4.w;
                acc[mt][1][0] += a1 * bv4.x; acc[mt][1][1] += a1 * bv4.y;
                acc[mt][1][2] += a1 * bv4.z; acc[mt][1][3] += a1 * bv4.w;
                acc[mt][2][0] += a2 * bv4.x; acc[mt][2][1] += a2 * bv4.y;
                acc[mt][2][2] += a2 * bv4.z; acc[mt][2][3] += a2 * bv4.w;
                acc[mt][3][0] += a3 * bv4.x; acc[mt][3][1] += a3 * bv4.y;
                acc[mt][3][2] += a3 * bv4.z; acc[mt][3][3] += a3 * bv4.w;
            }
        }
        __syncthreads();
    }

    // epilogue: + bias, float4 stores
    const float* bp[3]  = {bq, bk, bv};
    float*       op[3]  = {Qo, Ko, Vo};
    #pragma unroll
    for (int mt = 0; mt < 3; ++mt) {
        const float4 bias = *(const float4*)(bp[mt] + n0 + tx * 4);
        #pragma unroll
        for (int i = 0; i < 4; ++i) {
            float4 v;
            v.x = acc[mt][i][0] + bias.x;
            v.y = acc[mt][i][1] + bias.y;
            v.z = acc[mt][i][2] + bias.z;
            v.w = acc[mt][i][3] + bias.w;
            *(float4*)(op[mt] + (size_t)(m0 + ty * 4 + i) * H_ + n0 + tx * 4) = v;
        }
    }
}

// ---------------- edge attention (one block per segment (b,i)) ----------------
// Edges for segment s are contiguous: e in [s*DEG, (s+1)*DEG).
__global__ __launch_bounds__(256)
void edge_attn(const float* __restrict__ Qm, const float* __restrict__ Km,
               const float* __restrict__ Vm, const int* __restrict__ eidx,
               const float* __restrict__ Ek, const float* __restrict__ Ev,
               float* __restrict__ out)
{
    __shared__ float qs[H_];
    __shared__ int   jj[DEG_];
    __shared__ int   rr[DEG_];
    __shared__ float lg[DEG_][NH_];   // logits -> attn weights

    const int seg = blockIdx.x;
    const int b   = seg >> 8;         // N_ = 256
    const int t   = threadIdx.x;

    // phase 1: stage indices + Q row
    const int e0 = seg * DEG_;
    if (t < DEG_) {
        jj[t] = eidx[2 * E_ + e0 + t];
        rr[t] = eidx[3 * E_ + e0 + t];
    }
    {
        const float* qrow = Qm + (size_t)seg * H_;
        qs[t]       = qrow[t];
        qs[t + 256] = qrow[t + 256];
        qs[t + 512] = qrow[t + 512];
    }
    __syncthreads();

    // phase 2: logits. wave w handles edges [8w, 8w+8). lane l holds dim h*64+l per head h.
    const int wave = t >> 6;
    const int lane = t & 63;
    float qv[NH_];
    #pragma unroll
    for (int h = 0; h < NH_; ++h) qv[h] = qs[h * 64 + lane];

    const float scale = 0.125f;  // 1/sqrt(64)
    #pragma unroll 1
    for (int el = 0; el < 8; ++el) {
        const int e = wave * 8 + el;
        const int j = jj[e];
        const int r = rr[e];
        const float* krow  = Km + ((size_t)(b * N_ + j)) * H_;
        const float* ekrow = Ek + (size_t)r * H_;
        float p[NH_];
        #pragma unroll
        for (int h = 0; h < NH_; ++h)
            p[h] = qv[h] * (krow[h * 64 + lane] + ekrow[h * 64 + lane]);
        #pragma unroll
        for (int off = 32; off >= 1; off >>= 1) {
            #pragma unroll
            for (int h = 0; h < NH_; ++h)
                p[h] += __shfl_xor(p[h], off);
        }
        if (lane == 0) {
            #pragma unroll
            for (int h = 0; h < NH_; ++h) lg[e][h] = p[h] * scale;
        }
    }
    __syncthreads();

    // phase 3: softmax over the 32 edges, per head (12 threads, serial over 32 — tiny)
    if (t < NH_) {
        const int h = t;
        float m = -1e30f;
        for (int e = 0; e < DEG_; ++e) m = fmaxf(m, lg[e][h]);
        float z = 0.f;
        for (int e = 0; e < DEG_; ++e) {
            const float x = __expf(lg[e][h] - m);
            lg[e][h] = x;
            z += x;
        }
        const float inv = 1.f / z;
        for (int e = 0; e < DEG_; ++e) lg[e][h] *= inv;
    }
    __syncthreads();

    // phase 4: out[d] = sum_e attn[e][d/64] * (V[b,j_e][d] + Ev[r_e][d]); thread t owns d in {t, t+256, t+512}
    float acc0 = 0.f, acc1 = 0.f, acc2 = 0.f;
    const size_t bN = (size_t)b * N_;
    #pragma unroll 1
    for (int e = 0; e < DEG_; ++e) {
        const int j = jj[e];
        const int r = rr[e];
        const float* vrow  = Vm + (bN + j) * H_;
        const float* evrow = Ev + (size_t)r * H_;
        const float a0 = lg[e][ t        >> 6];
        const float a1 = lg[e][(t + 256) >> 6];
        const float a2 = lg[e][(t + 512) >> 6];
        acc0 += a0 * (vrow[t]       + evrow[t]);
        acc1 += a1 * (vrow[t + 256] + evrow[t + 256]);
        acc2 += a2 * (vrow[t + 512] + evrow[t + 512]);
    }
    float* orow = out + (size_t)seg * H_;
    orow[t]       = acc0;
    orow[t + 256] = acc1;
    orow[t + 512] = acc2;
}

extern "C" void kernel_launch(void* const* d_in, const int* in_sizes, int n_in,
                              void* d_out, int out_size, void* d_ws, size_t ws_size,
                              hipStream_t stream)
{
    const float* X    = (const float*)d_in[0];
    const int*   eidx = (const int*)  d_in[1];
    const float* Wq   = (const float*)d_in[2];
    const float* bq   = (const float*)d_in[3];
    const float* Wk   = (const float*)d_in[4];
    const float* bk   = (const float*)d_in[5];
    const float* Wv   = (const float*)d_in[6];
    const float* bv   = (const float*)d_in[7];
    const float* Ek   = (const float*)d_in[8];
    const float* Ev   = (const float*)d_in[9];
    float* out = (float*)d_out;

    float* Q = (float*)d_ws;                      // M_*H_ floats
    float* K = Q + (size_t)M_ * H_;
    float* V = K + (size_t)M_ * H_;               // total 3*2048*768*4B = 18.9 MB

    qkv_gemm<<<dim3(H_ / TN, M_ / TM), dim3(256), 0, stream>>>(
        X, Wq, bq, Wk, bk, Wv, bv, Q, K, V);
    edge_attn<<<dim3(M_), dim3(256), 0, stream>>>(
        Q, K, V, eidx, Ek, Ev, out);
}

// Round 2
// 171.433 us; speedup vs baseline: 1.5057x; 1.5057x over previous
//
#include <hip/hip_runtime.h>
#include <hip/hip_bf16.h>
#include <cstdint>
#include <cstddef>

// Problem constants (fixed by setup_inputs)
#define B_   8
#define N_   256
#define DEG_ 32
#define H_   768
#define NH_  12
#define DH_  64
#define R_   64
#define E_   (B_*N_*DEG_)   // 65536
#define M_   (B_*N_)        // 2048

typedef __attribute__((ext_vector_type(8))) short short8;
typedef __attribute__((ext_vector_type(4))) float float4v;

static __device__ __forceinline__ short f2bf(float f) {
    __hip_bfloat16 h = __float2bfloat16(f);
    return *(short*)&h;
}

// ---------------- cast X fp32 -> bf16 (row-major, k contiguous) ----------------
__global__ __launch_bounds__(256)
void cast_x(const float* __restrict__ X, short* __restrict__ Xb)
{
    const int i = (blockIdx.x * 256 + threadIdx.x) * 8;
    const float4 a = *(const float4*)(X + i);
    const float4 b = *(const float4*)(X + i + 4);
    short8 o;
    o[0] = f2bf(a.x); o[1] = f2bf(a.y); o[2] = f2bf(a.z); o[3] = f2bf(a.w);
    o[4] = f2bf(b.x); o[5] = f2bf(b.y); o[6] = f2bf(b.z); o[7] = f2bf(b.w);
    *(short8*)(Xb + i) = o;
}

// ------------- transpose + cast W[k][n] fp32 -> Wt[n][k] bf16 ------------------
__global__ __launch_bounds__(256)
void cast_wt(const float* __restrict__ W0, const float* __restrict__ W1,
             const float* __restrict__ W2, short* __restrict__ Wt)
{
    const float* W = (blockIdx.z == 0) ? W0 : (blockIdx.z == 1) ? W1 : W2;
    short* Wo = Wt + (size_t)blockIdx.z * H_ * H_;
    __shared__ short tile[64][66];   // [k][n], +2 pad
    const int kb = blockIdx.y * 64, nb = blockIdx.x * 64;
    const int t = threadIdx.x;
    {
        const int k = t >> 2, nq = (t & 3) * 16;
        const float* src = W + (size_t)(kb + k) * H_ + nb + nq;
        #pragma unroll
        for (int q = 0; q < 16; q += 4) {
            const float4 v = *(const float4*)(src + q);
            tile[k][nq + q + 0] = f2bf(v.x);
            tile[k][nq + q + 1] = f2bf(v.y);
            tile[k][nq + q + 2] = f2bf(v.z);
            tile[k][nq + q + 3] = f2bf(v.w);
        }
    }
    __syncthreads();
    {
        const int n = t >> 2, kq = (t & 3) * 16;
        short8 o0, o1;
        #pragma unroll
        for (int j = 0; j < 8; ++j) o0[j] = tile[kq + j][n];
        #pragma unroll
        for (int j = 0; j < 8; ++j) o1[j] = tile[kq + 8 + j][n];
        short* dst = Wo + (size_t)(nb + n) * H_ + kb + kq;
        *(short8*)dst = o0;
        *(short8*)(dst + 8) = o1;
    }
}

// ---------------- fused QKV GEMM via bf16 MFMA ----------------
// C(2048 x 2304) = Xb(2048x768) @ [Wq|Wk|Wv]; Wt stored [n][k] bf16.
#define BM 128
#define BN 64
#define BK 32
#define XP 40   // LDS pitch (shorts) for X tile
#define WP 40

__global__ __launch_bounds__(256, 2)
void qkv_mfma(const short* __restrict__ Xb, const short* __restrict__ Wt,
              const float* __restrict__ bq, const float* __restrict__ bk,
              const float* __restrict__ bv,
              float* __restrict__ Qo, float* __restrict__ Ko, float* __restrict__ Vo)
{
    __shared__ __align__(16) short Xs[BM * XP];
    __shared__ __align__(16) short Ws[BN * WP];
    const int t = threadIdx.x;
    const int wave = t >> 6, lane = t & 63;
    const int mt = blockIdx.x / 12;              // 0=Q,1=K,2=V
    const int n0 = (blockIdx.x % 12) * BN;
    const int m0 = blockIdx.y * BM;
    const short* Wm = Wt + (size_t)mt * H_ * H_; // [n][k]

    float4v acc[2][4];
    #pragma unroll
    for (int i = 0; i < 2; ++i)
        #pragma unroll
        for (int j = 0; j < 4; ++j)
            acc[i][j] = (float4v){0.f, 0.f, 0.f, 0.f};

    const int xr = t >> 1, xc = (t & 1) * 16;    // X staging: 2 thr/row, 16 el each
    const int wr = t >> 2, wc = (t & 3) * 8;     // W staging: 4 thr/row, 8 el each
    const int quad = lane >> 4, lr = lane & 15;

    for (int kt = 0; kt < H_; kt += BK) {
        {
            const short* src = Xb + (size_t)(m0 + xr) * H_ + kt + xc;
            const uint4 v0 = *(const uint4*)src;
            const uint4 v1 = *(const uint4*)(src + 8);
            *(uint4*)&Xs[xr * XP + xc] = v0;
            *(uint4*)&Xs[xr * XP + xc + 8] = v1;
        }
        {
            const short* src = Wm + (size_t)(n0 + wr) * H_ + kt + wc;
            *(uint4*)&Ws[wr * WP + wc] = *(const uint4*)src;
        }
        __syncthreads();

        short8 af[2], bf[4];
        af[0] = *(const short8*)&Xs[(wave * 32 + lr) * XP + quad * 8];
        af[1] = *(const short8*)&Xs[(wave * 32 + 16 + lr) * XP + quad * 8];
        #pragma unroll
        for (int c = 0; c < 4; ++c)
            bf[c] = *(const short8*)&Ws[(c * 16 + lr) * WP + quad * 8];

        #pragma unroll
        for (int rf = 0; rf < 2; ++rf)
            #pragma unroll
            for (int c = 0; c < 4; ++c)
                acc[rf][c] = __builtin_amdgcn_mfma_f32_16x16x32_bf16(
                    af[rf], bf[c], acc[rf][c], 0, 0, 0);
        __syncthreads();
    }

    const float* bp = (mt == 0) ? bq : (mt == 1) ? bk : bv;
    float*       op = (mt == 0) ? Qo : (mt == 1) ? Ko : Vo;
    #pragma unroll
    for (int rf = 0; rf < 2; ++rf) {
        #pragma unroll
        for (int c = 0; c < 4; ++c) {
            const int col = n0 + c * 16 + lr;
            const float bias = bp[col];
            #pragma unroll
            for (int r4 = 0; r4 < 4; ++r4) {
                const int row = m0 + wave * 32 + rf * 16 + quad * 4 + r4;
                op[(size_t)row * H_ + col] = acc[rf][c][r4] + bias;
            }
        }
    }
}

// ---------------- edge attention (one block per segment (b,i)) ----------------
__global__ __launch_bounds__(256)
void edge_attn(const float* __restrict__ Qm, const float* __restrict__ Km,
               const float* __restrict__ Vm, const int* __restrict__ eidx,
               const float* __restrict__ Ek, const float* __restrict__ Ev,
               float* __restrict__ out)
{
    __shared__ float qs[H_];
    __shared__ int   jj[DEG_];
    __shared__ int   rr[DEG_];
    __shared__ float lg[DEG_][NH_];

    const int seg = blockIdx.x;
    const int b   = seg >> 8;
    const int t   = threadIdx.x;
    const int e0  = seg * DEG_;

    if (t < DEG_) {
        jj[t] = eidx[2 * E_ + e0 + t];
        rr[t] = eidx[3 * E_ + e0 + t];
    }
    {
        const float* qrow = Qm + (size_t)seg * H_;
        qs[t]       = qrow[t];
        qs[t + 256] = qrow[t + 256];
        qs[t + 512] = qrow[t + 512];
    }
    __syncthreads();

    const int wave = t >> 6;
    const int lane = t & 63;
    const size_t bN = (size_t)b * N_;
    float qv[NH_];
    #pragma unroll
    for (int h = 0; h < NH_; ++h) qv[h] = qs[h * 64 + lane];

    // hoist this wave's 8 (j,r) pairs into registers so the unrolled loop
    // can put many independent global loads in flight
    int jv[8], rv[8];
    #pragma unroll
    for (int el = 0; el < 8; ++el) {
        jv[el] = jj[wave * 8 + el];
        rv[el] = rr[wave * 8 + el];
    }

    const float scale = 0.125f;  // 1/sqrt(64)
    #pragma unroll 2
    for (int el = 0; el < 8; ++el) {
        const float* krow = Km + (bN + jv[el]) * H_;
        const float* ekr  = Ek + (size_t)rv[el] * H_;
        float p[NH_];
        #pragma unroll
        for (int h = 0; h < NH_; ++h)
            p[h] = qv[h] * (krow[h * 64 + lane] + ekr[h * 64 + lane]);
        #pragma unroll
        for (int off = 32; off >= 1; off >>= 1) {
            #pragma unroll
            for (int h = 0; h < NH_; ++h)
                p[h] += __shfl_xor(p[h], off);
        }
        if (lane == 0) {
            #pragma unroll
            for (int h = 0; h < NH_; ++h) lg[wave * 8 + el][h] = p[h] * scale;
        }
    }
    __syncthreads();

    if (t < NH_) {
        const int h = t;
        float m = -1e30f;
        for (int e = 0; e < DEG_; ++e) m = fmaxf(m, lg[e][h]);
        float z = 0.f;
        for (int e = 0; e < DEG_; ++e) {
            const float x = __expf(lg[e][h] - m);
            lg[e][h] = x;
            z += x;
        }
        const float inv = 1.f / z;
        for (int e = 0; e < DEG_; ++e) lg[e][h] *= inv;
    }
    __syncthreads();

    float acc0 = 0.f, acc1 = 0.f, acc2 = 0.f;
    const int h0 = t >> 6, h1 = (t + 256) >> 6, h2 = (t + 512) >> 6;
    #pragma unroll 4
    for (int e = 0; e < DEG_; ++e) {
        const int j = jj[e];
        const int r = rr[e];
        const float* vrow = Vm + (bN + j) * H_;
        const float* evr  = Ev + (size_t)r * H_;
        const float a0 = lg[e][h0];
        const float a1 = lg[e][h1];
        const float a2 = lg[e][h2];
        acc0 += a0 * (vrow[t]       + evr[t]);
        acc1 += a1 * (vrow[t + 256] + evr[t + 256]);
        acc2 += a2 * (vrow[t + 512] + evr[t + 512]);
    }
    float* orow = out + (size_t)seg * H_;
    orow[t]       = acc0;
    orow[t + 256] = acc1;
    orow[t + 512] = acc2;
}

extern "C" void kernel_launch(void* const* d_in, const int* in_sizes, int n_in,
                              void* d_out, int out_size, void* d_ws, size_t ws_size,
                              hipStream_t stream)
{
    const float* X    = (const float*)d_in[0];
    const int*   eidx = (const int*)  d_in[1];
    const float* Wq   = (const float*)d_in[2];
    const float* bq   = (const float*)d_in[3];
    const float* Wk   = (const float*)d_in[4];
    const float* bk   = (const float*)d_in[5];
    const float* Wv   = (const float*)d_in[6];
    const float* bv   = (const float*)d_in[7];
    const float* Ek   = (const float*)d_in[8];
    const float* Ev   = (const float*)d_in[9];
    float* out = (float*)d_out;

    // workspace layout
    float* Q  = (float*)d_ws;                       // 1.57M floats
    float* K  = Q + (size_t)M_ * H_;
    float* V  = K + (size_t)M_ * H_;
    short* Xb = (short*)(V + (size_t)M_ * H_);      // 2048x768 bf16
    short* Wt = Xb + (size_t)M_ * H_;               // 3 x 768x768 bf16 [n][k]

    cast_x<<<dim3(M_ * H_ / (256 * 8)), dim3(256), 0, stream>>>(X, Xb);
    cast_wt<<<dim3(H_ / 64, H_ / 64, 3), dim3(256), 0, stream>>>(Wq, Wk, Wv, Wt);
    qkv_mfma<<<dim3(3 * H_ / BN, M_ / BM), dim3(256), 0, stream>>>(
        Xb, Wt, bq, bk, bv, Q, K, V);
    edge_attn<<<dim3(M_), dim3(256), 0, stream>>>(Q, K, V, eidx, Ek, Ev, out);
}

// Round 3
// 134.078 us; speedup vs baseline: 1.9252x; 1.2786x over previous
//
#include <hip/hip_runtime.h>
#include <hip/hip_bf16.h>
#include <cstdint>
#include <cstddef>

// Problem constants (fixed by setup_inputs)
#define B_   8
#define N_   256
#define DEG_ 32
#define H_   768
#define NH_  12
#define E_   (B_*N_*DEG_)   // 65536
#define M_   (B_*N_)        // 2048

typedef __attribute__((ext_vector_type(8))) short short8;
typedef __attribute__((ext_vector_type(4))) float float4v;

static __device__ __forceinline__ short f2bf(float f) {
    __hip_bfloat16 h = __float2bfloat16(f);
    return *(short*)&h;
}

// ------------- transpose + cast W[k][n] fp32 -> Wt[n][k] bf16 ------------------
__global__ __launch_bounds__(256)
void cast_wt(const float* __restrict__ W0, const float* __restrict__ W1,
             const float* __restrict__ W2, short* __restrict__ Wt)
{
    const float* W = (blockIdx.z == 0) ? W0 : (blockIdx.z == 1) ? W1 : W2;
    short* Wo = Wt + (size_t)blockIdx.z * H_ * H_;
    __shared__ short tile[64][65];   // odd pitch -> conflict-light transpose reads
    const int kb = blockIdx.y * 64, nb = blockIdx.x * 64;
    const int t = threadIdx.x;
    {
        const int k = t >> 2, nq = (t & 3) * 16;
        const float* src = W + (size_t)(kb + k) * H_ + nb + nq;
        #pragma unroll
        for (int q = 0; q < 16; q += 4) {
            const float4 v = *(const float4*)(src + q);
            tile[k][nq + q + 0] = f2bf(v.x);
            tile[k][nq + q + 1] = f2bf(v.y);
            tile[k][nq + q + 2] = f2bf(v.z);
            tile[k][nq + q + 3] = f2bf(v.w);
        }
    }
    __syncthreads();
    {
        const int n = t >> 2, kq = (t & 3) * 16;
        short8 o0, o1;
        #pragma unroll
        for (int j = 0; j < 8; ++j) o0[j] = tile[kq + j][n];
        #pragma unroll
        for (int j = 0; j < 8; ++j) o1[j] = tile[kq + 8 + j][n];
        short* dst = Wo + (size_t)(nb + n) * H_ + kb + kq;
        *(short8*)dst = o0;
        *(short8*)(dst + 8) = o1;
    }
}

// ---------------- fused QKV GEMM via bf16 MFMA ----------------
// C(2048 x 2304) = X(2048x768, fp32 cast inline) @ [Wq|Wk|Wv]; Wt is [n][k] bf16.
// BM=BN=64, BK=32, 4 waves each computing a 32x32 quadrant (2x2 16x16x32 frags).
#define BK 32
#define XP 40   // LDS pitch in shorts (80B: 16B-aligned rows, 2-way banks = free)
#define WP 40

__global__ __launch_bounds__(256, 4)
void qkv_mfma(const float* __restrict__ X, const short* __restrict__ Wt,
              const float* __restrict__ bq, const float* __restrict__ bk,
              const float* __restrict__ bv,
              float* __restrict__ Qo, float* __restrict__ Ko, float* __restrict__ Vo)
{
    __shared__ __align__(16) short Xs[64 * XP];
    __shared__ __align__(16) short Ws[64 * WP];
    const int t = threadIdx.x;

    // 1D grid 1152, decoded so each XCD owns 4 consecutive m-rows (X L2 locality)
    const int L    = blockIdx.x;
    const int xcd  = L & 7, slot = L >> 3;      // slot 0..143
    const int by   = xcd * 4 + (slot & 3);      // 0..31
    const int bx   = slot >> 2;                 // 0..35
    const int mt   = bx / 12;                   // 0=Q,1=K,2=V
    const int n0   = (bx % 12) * 64;
    const int m0   = by * 64;
    const short* Wm = Wt + (size_t)mt * H_ * H_;

    const int wave = t >> 6, lane = t & 63;
    const int wr = wave >> 1, wc = wave & 1;    // 2x2 wave grid
    const int quad = lane >> 4, lr = lane & 15;

    float4v acc[2][2];
    #pragma unroll
    for (int i = 0; i < 2; ++i)
        #pragma unroll
        for (int j = 0; j < 2; ++j)
            acc[i][j] = (float4v){0.f, 0.f, 0.f, 0.f};

    const int xrow = t >> 2, xk = (t & 3) * 8;  // X staging: 4 thr/row, 8 k each
    const int wn   = t >> 2, wk = (t & 3) * 8;  // W staging: 4 thr/row, 8 k each

    for (int kt = 0; kt < H_; kt += BK) {
        {   // X: fp32 load + cast + bf16 LDS write
            const float* src = X + (size_t)(m0 + xrow) * H_ + kt + xk;
            const float4 a = *(const float4*)src;
            const float4 b = *(const float4*)(src + 4);
            short8 o;
            o[0] = f2bf(a.x); o[1] = f2bf(a.y); o[2] = f2bf(a.z); o[3] = f2bf(a.w);
            o[4] = f2bf(b.x); o[5] = f2bf(b.y); o[6] = f2bf(b.z); o[7] = f2bf(b.w);
            *(short8*)&Xs[xrow * XP + xk] = o;
        }
        {   // W: bf16 row load (k-contiguous) + LDS write
            const short8 v = *(const short8*)(Wm + (size_t)(n0 + wn) * H_ + kt + wk);
            *(short8*)&Ws[wn * WP + wk] = v;
        }
        __syncthreads();

        short8 af[2], bf[2];
        #pragma unroll
        for (int i = 0; i < 2; ++i)
            af[i] = *(const short8*)&Xs[(wr * 32 + i * 16 + lr) * XP + quad * 8];
        #pragma unroll
        for (int j = 0; j < 2; ++j)
            bf[j] = *(const short8*)&Ws[(wc * 32 + j * 16 + lr) * WP + quad * 8];

        #pragma unroll
        for (int i = 0; i < 2; ++i)
            #pragma unroll
            for (int j = 0; j < 2; ++j)
                acc[i][j] = __builtin_amdgcn_mfma_f32_16x16x32_bf16(
                    af[i], bf[j], acc[i][j], 0, 0, 0);
        __syncthreads();
    }

    const float* bp = (mt == 0) ? bq : (mt == 1) ? bk : bv;
    float*       op = (mt == 0) ? Qo : (mt == 1) ? Ko : Vo;
    #pragma unroll
    for (int i = 0; i < 2; ++i) {
        #pragma unroll
        for (int j = 0; j < 2; ++j) {
            const int col = n0 + wc * 32 + j * 16 + lr;
            const float bias = bp[col];
            #pragma unroll
            for (int r4 = 0; r4 < 4; ++r4) {
                const int row = m0 + wr * 32 + i * 16 + quad * 4 + r4;
                op[(size_t)row * H_ + col] = acc[i][j][r4] + bias;
            }
        }
    }
}

// ---------------- edge attention (one block per segment (b,i)) ----------------
// 16 lanes per edge (float4 per lane), 4 edges per wave in parallel.
__global__ __launch_bounds__(256)
void edge_attn(const float* __restrict__ Qm, const float* __restrict__ Km,
               const float* __restrict__ Vm, const int* __restrict__ eidx,
               const float* __restrict__ Ek, const float* __restrict__ Ev,
               float* __restrict__ out)
{
    __shared__ __align__(16) float qs[H_];
    __shared__ int   jj[DEG_];
    __shared__ int   rr[DEG_];
    __shared__ float lg[DEG_][13];   // odd pitch

    // XCD swizzle: batch b pinned to one XCD -> K/V live in that XCD's L2
    const int bid = blockIdx.x;
    const int seg = ((bid & 7) << 8) | (bid >> 3);
    const int b   = seg >> 8;
    const int t   = threadIdx.x;
    const int e0  = seg * DEG_;

    // phase 1: stage Q row (192 thr, float4) + indices (64 thr) in parallel
    if (t < 192) {
        ((float4*)qs)[t] = ((const float4*)(Qm + (size_t)seg * H_))[t];
    } else if (t < 224) {
        jj[t - 192] = eidx[2 * E_ + e0 + (t - 192)];
    } else {
        rr[t - 224] = eidx[3 * E_ + e0 + (t - 224)];
    }
    __syncthreads();

    const int wave = t >> 6, lane = t & 63;
    const int sub = lane >> 4, l16 = lane & 15;   // 4 edges/wave, 16 lanes/edge
    const size_t bN = (size_t)b * N_;

    float4 q4[NH_];
    #pragma unroll
    for (int h = 0; h < NH_; ++h)
        q4[h] = *(const float4*)&qs[h * 64 + l16 * 4];

    const float scale = 0.125f;  // 1/sqrt(64)
    #pragma unroll
    for (int it = 0; it < 2; ++it) {
        const int e = it * 16 + wave * 4 + sub;
        const int j = jj[e], r = rr[e];
        const float* kr = Km + (bN + j) * H_ + l16 * 4;
        const float* er = Ek + (size_t)r * H_ + l16 * 4;
        float p[NH_];
        #pragma unroll
        for (int h = 0; h < NH_; ++h) {
            const float4 kv = *(const float4*)(kr + h * 64);
            const float4 ev = *(const float4*)(er + h * 64);
            p[h] = q4[h].x * (kv.x + ev.x) + q4[h].y * (kv.y + ev.y)
                 + q4[h].z * (kv.z + ev.z) + q4[h].w * (kv.w + ev.w);
        }
        #pragma unroll
        for (int off = 8; off >= 1; off >>= 1)
            #pragma unroll
            for (int h = 0; h < NH_; ++h)
                p[h] += __shfl_xor(p[h], off);
        if (l16 == 0) {
            #pragma unroll
            for (int h = 0; h < NH_; ++h) lg[e][h] = p[h] * scale;
        }
    }
    __syncthreads();

    // phase 3: softmax, parallel over (head, 16 lanes); each lane owns 2 edges
    if (t < 192) {
        const int h = t >> 4, l = t & 15;
        const float a = lg[l][h], c = lg[l + 16][h];
        float m = fmaxf(a, c);
        #pragma unroll
        for (int off = 8; off >= 1; off >>= 1) m = fmaxf(m, __shfl_xor(m, off));
        const float ea = __expf(a - m), ec = __expf(c - m);
        float z = ea + ec;
        #pragma unroll
        for (int off = 8; off >= 1; off >>= 1) z += __shfl_xor(z, off);
        const float inv = 1.f / z;
        lg[l][h] = ea * inv;
        lg[l + 16][h] = ec * inv;
    }
    __syncthreads();

    // phase 4: out[4t..4t+3] = sum_e attn[e][h] * (V[b,j_e] + Ev[r_e]) ; 192 thr x float4
    if (t < 192) {
        const int h = t >> 4;
        const float* vbase  = Vm + bN * H_ + 4 * t;
        const float* evbase = Ev + 4 * t;
        float4 acc = {0.f, 0.f, 0.f, 0.f};
        #pragma unroll 4
        for (int e = 0; e < DEG_; ++e) {
            const float a = lg[e][h];
            const float4 v  = *(const float4*)(vbase  + (size_t)jj[e] * H_);
            const float4 ev = *(const float4*)(evbase + (size_t)rr[e] * H_);
            acc.x += a * (v.x + ev.x);
            acc.y += a * (v.y + ev.y);
            acc.z += a * (v.z + ev.z);
            acc.w += a * (v.w + ev.w);
        }
        *(float4*)(out + (size_t)seg * H_ + 4 * t) = acc;
    }
}

extern "C" void kernel_launch(void* const* d_in, const int* in_sizes, int n_in,
                              void* d_out, int out_size, void* d_ws, size_t ws_size,
                              hipStream_t stream)
{
    const float* X    = (const float*)d_in[0];
    const int*   eidx = (const int*)  d_in[1];
    const float* Wq   = (const float*)d_in[2];
    const float* bq   = (const float*)d_in[3];
    const float* Wk   = (const float*)d_in[4];
    const float* bk   = (const float*)d_in[5];
    const float* Wv   = (const float*)d_in[6];
    const float* bv   = (const float*)d_in[7];
    const float* Ek   = (const float*)d_in[8];
    const float* Ev   = (const float*)d_in[9];
    float* out = (float*)d_out;

    float* Q  = (float*)d_ws;                      // 3 x M_*H_ fp32
    float* K  = Q + (size_t)M_ * H_;
    float* V  = K + (size_t)M_ * H_;
    short* Wt = (short*)(V + (size_t)M_ * H_);     // 3 x H_*H_ bf16 [n][k]

    cast_wt<<<dim3(H_ / 64, H_ / 64, 3), dim3(256), 0, stream>>>(Wq, Wk, Wv, Wt);
    qkv_mfma<<<dim3(1152), dim3(256), 0, stream>>>(X, Wt, bq, bk, bv, Q, K, V);
    edge_attn<<<dim3(M_), dim3(256), 0, stream>>>(Q, K, V, eidx, Ek, Ev, out);
}